// Round 1
// baseline (2440.241 us; speedup 1.0000x reference)
//
#include <hip/hip_runtime.h>
#include <math.h>

#define NLOC 20000
#define TT   24
#define INDIM 18
#define HH   32
#define PWN  15

__device__ __forceinline__ unsigned int fkey(float f) {
    unsigned int b = __float_as_uint(f);
    return b ^ ((unsigned int)((int)b >> 31) | 0x80000000u);
}
__device__ __forceinline__ float funkey(unsigned int u) {
    return (u & 0x80000000u) ? __uint_as_float(u ^ 0x80000000u) : __uint_as_float(~u);
}

// ---------------- CSR build ----------------
__global__ void count_kernel(const int* __restrict__ dst, int* __restrict__ cnt, int E) {
    int e = blockIdx.x * blockDim.x + threadIdx.x;
    if (e < E) atomicAdd(&cnt[dst[e]], 1);
}

__global__ void scan_kernel(const int* __restrict__ cnt, int* __restrict__ row_ptr, int n) {
    __shared__ int sums[1024];
    const int CH = 20; // 1024*20 = 20480 >= 20000
    int tid = threadIdx.x;
    int base = tid * CH;
    int local[CH];
    int s = 0;
    #pragma unroll
    for (int i = 0; i < CH; ++i) {
        int idx = base + i;
        int v = (idx < n) ? cnt[idx] : 0;
        local[i] = s;
        s += v;
    }
    sums[tid] = s;
    __syncthreads();
    for (int o = 1; o < 1024; o <<= 1) {
        int v = (tid >= o) ? sums[tid - o] : 0;
        __syncthreads();
        sums[tid] += v;
        __syncthreads();
    }
    int pre = (tid > 0) ? sums[tid - 1] : 0;
    #pragma unroll
    for (int i = 0; i < CH; ++i) {
        int idx = base + i;
        if (idx < n) row_ptr[idx] = pre + local[i];
    }
    if (tid == 1023) row_ptr[n] = sums[1023];
}

__global__ void scatter_kernel(const int* __restrict__ src, const int* __restrict__ dst,
                               const int* __restrict__ row_ptr, int* __restrict__ fill,
                               int* __restrict__ csr_src, int E) {
    int e = blockIdx.x * blockDim.x + threadIdx.x;
    if (e < E) {
        int d = dst[e];
        int pos = row_ptr[d] + atomicAdd(&fill[d], 1);
        csr_src[pos] = src[e];
    }
}

// ---------------- node transform: z = x@W.T + b ; es/ed = aW-dots (ab folded into ed)
template<int IN>
__global__ void node_kernel(const float* __restrict__ x, int x_stride,
                            const float* __restrict__ W, const float* __restrict__ b,
                            const float* __restrict__ aW, const float* __restrict__ ab,
                            float* __restrict__ z, float* __restrict__ es, float* __restrict__ ed,
                            unsigned int* __restrict__ pooled_init) {
    __shared__ float sW[HH * IN];
    __shared__ float sb[HH];
    __shared__ float saW[2 * HH];
    __shared__ float sab;
    int tid = threadIdx.x;
    for (int i = tid; i < HH * IN; i += blockDim.x) sW[i] = W[i];
    if (tid < HH) sb[tid] = b[tid];
    if (tid < 2 * HH) saW[tid] = aW[tid];
    if (tid == 0) sab = ab[0];
    if (pooled_init && blockIdx.x == 0 && tid < HH) pooled_init[tid * 64] = 0u;
    __syncthreads();
    int n = blockIdx.x * blockDim.x + tid;
    if (n >= NLOC) return;
    float xr[IN];
    const float* xp = x + (long)n * x_stride;
    #pragma unroll
    for (int i = 0; i < IN; ++i) xr[i] = xp[i];
    float e_s = 0.f, e_d = sab;
    #pragma unroll
    for (int k = 0; k < HH; ++k) {
        float acc = sb[k];
        #pragma unroll
        for (int i = 0; i < IN; ++i) acc = fmaf(xr[i], sW[k * IN + i], acc);
        z[n * HH + k] = acc;
        e_s = fmaf(saW[k], acc, e_s);
        e_d = fmaf(saW[HH + k], acc, e_d);
    }
    es[n] = e_s;
    ed[n] = e_d;
}

// ---------------- per-dst attention aggregation + elu (+ optional block max-pool)
__global__ void agg_kernel(const int* __restrict__ row_ptr, const int* __restrict__ csr_src,
                           const float* __restrict__ z, const float* __restrict__ es,
                           const float* __restrict__ ed, float* __restrict__ cout,
                           unsigned int* __restrict__ pooled_u) {
    __shared__ float red[512];
    int lane = threadIdx.x & 31;
    int grp  = threadIdx.x >> 5;
    int d = blockIdx.x * (blockDim.x >> 5) + grp;
    float cval = -3.4e38f;
    if (d < NLOC) {
        int beg = row_ptr[d], end = row_ptr[d + 1];
        float edd = ed[d];
        float den = 0.f, acc = 0.f;
        for (int i = beg; i < end; ++i) {
            int s = csr_src[i];
            float e = es[s] + edd;
            e = (e > 0.f) ? e : 0.01f * e;          // leaky_relu(0.01)
            float ex = __expf(e);                    // softmax without max-shift (logits O(1))
            den += ex;
            acc = fmaf(ex, z[s * HH + lane], acc);
        }
        float v = acc / den;
        cval = (v > 0.f) ? v : expm1f(v);            // elu
        cout[d * HH + lane] = cval;
    }
    if (pooled_u) {
        red[threadIdx.x] = cval;
        __syncthreads();
        for (int off = 256; off >= 32; off >>= 1) {
            if ((int)threadIdx.x < off) red[threadIdx.x] = fmaxf(red[threadIdx.x], red[threadIdx.x + off]);
            __syncthreads();
        }
        if (threadIdx.x < 32) atomicMax(&pooled_u[threadIdx.x * 64], fkey(red[threadIdx.x]));
    }
}

// ---------------- GRU cell + heads (single block, 128 threads)
__global__ void gru_kernel(const unsigned int* __restrict__ pooled_u,
                           const float* __restrict__ Wih, const float* __restrict__ Whh,
                           const float* __restrict__ bih, const float* __restrict__ bhh,
                           const float* __restrict__ WI, const float* __restrict__ bI,
                           const float* __restrict__ WR, const float* __restrict__ bR,
                           const float* __restrict__ Ws, const float* __restrict__ bs,
                           const float* __restrict__ cIv, const float* __restrict__ cRv,
                           float* __restrict__ h, float* __restrict__ ab_out,
                           float* __restrict__ out_newI, float* __restrict__ out_newR,
                           float* __restrict__ h_fin, int t) {
    __shared__ float pooled[HH], hs[HH], gi[96], gh[96], hc[34];
    int tid = threadIdx.x;
    if (tid < HH) {
        pooled[tid] = funkey(pooled_u[tid * 64]);
        hs[tid] = h[tid];
    }
    __syncthreads();
    if (tid < 96) {
        float a = bih[tid], g = bhh[tid];
        #pragma unroll
        for (int k = 0; k < HH; ++k) {
            a = fmaf(Wih[tid * HH + k], pooled[k], a);
            g = fmaf(Whh[tid * HH + k], hs[k], g);
        }
        gi[tid] = a; gh[tid] = g;
    }
    __syncthreads();
    if (tid < HH) {
        float r  = 1.f / (1.f + expf(-(gi[tid] + gh[tid])));
        float zg = 1.f / (1.f + expf(-(gi[HH + tid] + gh[HH + tid])));
        float nn = tanhf(gi[2 * HH + tid] + r * gh[2 * HH + tid]);
        float hn = (1.f - zg) * nn + zg * hs[tid];
        h[tid] = hn;
        hc[tid] = hn;
        if (h_fin) h_fin[tid] = hn;
    }
    if (tid == 32) hc[32] = cIv[t];
    if (tid == 33) hc[33] = cRv[t];
    __syncthreads();
    if (tid < PWN) {
        float a = bI[tid];
        #pragma unroll
        for (int k = 0; k < 34; ++k) a = fmaf(WI[tid * 34 + k], hc[k], a);
        out_newI[tid] = a;
    } else if (tid >= 32 && tid < 32 + PWN) {
        int p = tid - 32;
        float a = bR[p];
        #pragma unroll
        for (int k = 0; k < 34; ++k) a = fmaf(WR[p * 34 + k], hc[k], a);
        out_newR[p] = a;
    } else if (tid == 64 || tid == 65) {
        int p = tid - 64;
        float a = bs[p];
        #pragma unroll
        for (int k = 0; k < 34; ++k) a = fmaf(Ws[p * 34 + k], hc[k], a);
        ab_out[p] = 1.f / (1.f + expf(-a));
    }
}

// ---------------- SIR rollout for all (n, t) at once
__global__ void sir_kernel(const float* __restrict__ Nin, const float* __restrict__ Iv,
                           const float* __restrict__ Rv, const float* __restrict__ abArr,
                           float* __restrict__ phyI, float* __restrict__ phyR) {
    int idx = blockIdx.x * blockDim.x + threadIdx.x; // n*TT + t
    if (idx >= NLOC * TT) return;
    int n = idx / TT, t = idx - n * TT;
    float Nv = Nin[n];
    float alpha = abArr[2 * t], beta = abArr[2 * t + 1];
    float lI = Iv[t], lR = Rv[t];
    float* oI = phyI + (size_t)idx * PWN;
    float* oR = phyR + (size_t)idx * PWN;
    #pragma unroll
    for (int p = 0; p < PWN; ++p) {
        float lS = Nv - lI - lR;
        float dI = alpha * lI * (lS / Nv) - beta * lI;
        float dR = beta * lI;
        oI[p] = dI;
        oR[p] = dR;
        lI += dI;
        lR += dR;
    }
}

extern "C" void kernel_launch(void* const* d_in, const int* in_sizes, int n_in,
                              void* d_out, int out_size, void* d_ws, size_t ws_size,
                              hipStream_t stream) {
    const float* dynamic = (const float*)d_in[0];
    const float* cIv = (const float*)d_in[1];
    const float* cRv = (const float*)d_in[2];
    const float* Nin = (const float*)d_in[3];
    const float* Iv  = (const float*)d_in[4];
    const float* Rv  = (const float*)d_in[5];
    const float* h0  = (const float*)d_in[6];
    const float* W1  = (const float*)d_in[7];
    const float* b1  = (const float*)d_in[8];
    const float* aW1 = (const float*)d_in[9];
    const float* ab1 = (const float*)d_in[10];
    const float* W2  = (const float*)d_in[11];
    const float* b2  = (const float*)d_in[12];
    const float* aW2 = (const float*)d_in[13];
    const float* ab2 = (const float*)d_in[14];
    const float* Wih = (const float*)d_in[15];
    const float* Whh = (const float*)d_in[16];
    const float* bih = (const float*)d_in[17];
    const float* bhh = (const float*)d_in[18];
    const float* WI  = (const float*)d_in[19];
    const float* bI  = (const float*)d_in[20];
    const float* WR  = (const float*)d_in[21];
    const float* bR  = (const float*)d_in[22];
    const float* Ws  = (const float*)d_in[23];
    const float* bs  = (const float*)d_in[24];
    const int* esrc  = (const int*)d_in[25];
    const int* edst  = (const int*)d_in[26];
    const int E = in_sizes[25];

    float* out = (float*)d_out;
    float* out_newI = out;                         // (1,24,15)
    float* out_newR = out + TT * PWN;              // (1,24,15)
    float* phyI = out + 2 * TT * PWN;              // (20000,24,15)
    float* phyR = phyI + (size_t)NLOC * TT * PWN;
    float* h_fin = phyR + (size_t)NLOC * TT * PWN; // (1,32)

    // workspace layout
    int* cnt = (int*)d_ws;                // 20000
    int* fill = cnt + NLOC;               // 20000
    int* row_ptr = fill + NLOC;           // 20001 (+1 pad)
    int* csr = row_ptr + NLOC + 2;        // E
    float* es = (float*)(csr + E);        // 20000
    float* ed = es + NLOC;                // 20000
    float* zbuf = ed + NLOC;              // 20000*32
    float* cbuf = zbuf + NLOC * HH;       // 20000*32
    unsigned int* pooled_u = (unsigned int*)(cbuf + NLOC * HH); // 32*64
    float* hbuf = (float*)(pooled_u + 32 * 64); // 32
    float* abArr = hbuf + 32;             // 2*TT

    hipMemsetAsync(cnt, 0, 2 * NLOC * sizeof(int), stream);
    int egrid = (E + 255) / 256;
    count_kernel<<<egrid, 256, 0, stream>>>(edst, cnt, E);
    scan_kernel<<<1, 1024, 0, stream>>>(cnt, row_ptr, NLOC);
    scatter_kernel<<<egrid, 256, 0, stream>>>(esrc, edst, row_ptr, fill, csr, E);
    hipMemcpyAsync(hbuf, h0, HH * sizeof(float), hipMemcpyDeviceToDevice, stream);

    const int ngrid = (NLOC + 255) / 256;   // 79
    const int agrid = (NLOC + 15) / 16;     // 1250 (512 threads = 16 groups)

    for (int t = 0; t < TT; ++t) {
        node_kernel<INDIM><<<ngrid, 256, 0, stream>>>(dynamic + t * INDIM, TT * INDIM,
                                                      W1, b1, aW1, ab1, zbuf, es, ed, nullptr);
        agg_kernel<<<agrid, 512, 0, stream>>>(row_ptr, csr, zbuf, es, ed, cbuf, nullptr);
        node_kernel<HH><<<ngrid, 256, 0, stream>>>(cbuf, HH,
                                                   W2, b2, aW2, ab2, zbuf, es, ed, pooled_u);
        agg_kernel<<<agrid, 512, 0, stream>>>(row_ptr, csr, zbuf, es, ed, cbuf, pooled_u);
        gru_kernel<<<1, 128, 0, stream>>>(pooled_u, Wih, Whh, bih, bhh,
                                          WI, bI, WR, bR, Ws, bs, cIv, cRv,
                                          hbuf, abArr + 2 * t,
                                          out_newI + t * PWN, out_newR + t * PWN,
                                          (t == TT - 1) ? h_fin : nullptr, t);
    }
    sir_kernel<<<(NLOC * TT + 255) / 256, 256, 0, stream>>>(Nin, Iv, Rv, abArr, phyI, phyR);
}

// Round 2
// 1532.329 us; speedup vs baseline: 1.5925x; 1.5925x over previous
//
#include <hip/hip_runtime.h>
#include <math.h>
#include <float.h>

#define NLOC 20000
#define TT   24
#define INDIM 18
#define HH   32
#define PWN  15
#define PSTR 32   // uint stride between pooled keys (128B) to spread atomic lines

__device__ __forceinline__ unsigned int fkey(float f) {
    unsigned int b = __float_as_uint(f);
    return b ^ ((unsigned int)((int)b >> 31) | 0x80000000u);
}
__device__ __forceinline__ float funkey(unsigned int u) {
    return (u & 0x80000000u) ? __uint_as_float(u ^ 0x80000000u) : __uint_as_float(~u);
}

// ---------------- CSR build ----------------
__global__ void count_kernel(const int* __restrict__ dst, int* __restrict__ cnt, int E) {
    int e = blockIdx.x * blockDim.x + threadIdx.x;
    if (e < E) atomicAdd(&cnt[dst[e]], 1);
}

__global__ void scan_kernel(const int* __restrict__ cnt, int* __restrict__ row_ptr, int n) {
    __shared__ int sums[1024];
    const int CH = 20;
    int tid = threadIdx.x;
    int base = tid * CH;
    int local[CH];
    int s = 0;
    #pragma unroll
    for (int i = 0; i < CH; ++i) {
        int idx = base + i;
        int v = (idx < n) ? cnt[idx] : 0;
        local[i] = s;
        s += v;
    }
    sums[tid] = s;
    __syncthreads();
    for (int o = 1; o < 1024; o <<= 1) {
        int v = (tid >= o) ? sums[tid - o] : 0;
        __syncthreads();
        sums[tid] += v;
        __syncthreads();
    }
    int pre = (tid > 0) ? sums[tid - 1] : 0;
    #pragma unroll
    for (int i = 0; i < CH; ++i) {
        int idx = base + i;
        if (idx < n) row_ptr[idx] = pre + local[i];
    }
    if (tid == 1023) row_ptr[n] = sums[1023];
}

__global__ void scatter_kernel(const int* __restrict__ src, const int* __restrict__ dst,
                               const int* __restrict__ row_ptr, int* __restrict__ fill,
                               int* __restrict__ csr_src, int E) {
    int e = blockIdx.x * blockDim.x + threadIdx.x;
    if (e < E) {
        int d = dst[e];
        int pos = row_ptr[d] + atomicAdd(&fill[d], 1);
        csr_src[pos] = src[e];
    }
}

// ---------------- node transform (batched over timesteps via grid.y)
// x addr = xbase + n*nstride + (tadd + lt)*tstride
template<int IN>
__global__ void node_kernel(const float* __restrict__ xbase, long nstride, long tstride, int tadd,
                            const float* __restrict__ W, const float* __restrict__ b,
                            const float* __restrict__ aW, const float* __restrict__ ab,
                            float* __restrict__ z, float* __restrict__ es, float* __restrict__ ed) {
    __shared__ float sW[HH * IN];
    __shared__ float sb[HH];
    __shared__ float saW[2 * HH];
    __shared__ float sab;
    int tid = threadIdx.x;
    int lt = blockIdx.y;
    for (int i = tid; i < HH * IN; i += blockDim.x) sW[i] = W[i];
    if (tid < HH) sb[tid] = b[tid];
    if (tid < 2 * HH) saW[tid] = aW[tid];
    if (tid == 0) sab = ab[0];
    __syncthreads();
    int n = blockIdx.x * blockDim.x + tid;
    if (n >= NLOC) return;
    z  += (size_t)lt * NLOC * HH;
    es += (size_t)lt * NLOC;
    ed += (size_t)lt * NLOC;
    float xr[IN];
    const float* xp = xbase + (long)n * nstride + (long)(tadd + lt) * tstride;
    #pragma unroll
    for (int i = 0; i < IN; ++i) xr[i] = xp[i];
    float e_s = 0.f, e_d = sab;
    #pragma unroll
    for (int k = 0; k < HH; ++k) {
        float acc = sb[k];
        #pragma unroll
        for (int i = 0; i < IN; ++i) acc = fmaf(xr[i], sW[k * IN + i], acc);
        z[n * HH + k] = acc;
        e_s = fmaf(saW[k], acc, e_s);
        e_d = fmaf(saW[HH + k], acc, e_d);
    }
    es[n] = e_s;
    ed[n] = e_d;
}

// ---------------- per-dst attention aggregation (+elu) — wave-per-dst, batched over t
// 256 threads = 4 waves; each wave: 64 lanes = 2 edge-halves x 32 dims.
template<bool WRITE_C, bool POOL>
__global__ void agg_kernel(const int* __restrict__ row_ptr, const int* __restrict__ csr_src,
                           const float* __restrict__ z, const float* __restrict__ es,
                           const float* __restrict__ ed, float* __restrict__ cout,
                           unsigned int* __restrict__ pooled_u, int tbase) {
    __shared__ float sred[4][HH];
    int lt = blockIdx.y;
    int lane = threadIdx.x & 63;
    int w    = threadIdx.x >> 6;
    int j    = lane & 31;
    int half = lane >> 5;
    int d = blockIdx.x * 4 + w;
    z  += (size_t)lt * NLOC * HH;
    es += (size_t)lt * NLOC;
    ed += (size_t)lt * NLOC;

    float cval = -FLT_MAX;
    if (d < NLOC) {
        int beg = row_ptr[d], end = row_ptr[d + 1];
        float edd = ed[d];
        float den = 0.f, acc = 0.f;
        int i = beg + half;
        for (; i + 2 < end; i += 4) {          // 2 edges per half per iter (4 gathers in flight)
            int s0 = csr_src[i];
            int s1 = csr_src[i + 2];
            float a0 = es[s0], a1 = es[s1];
            float z0 = z[s0 * HH + j], z1 = z[s1 * HH + j];
            float e0 = a0 + edd; e0 = (e0 > 0.f) ? e0 : 0.01f * e0;
            float e1 = a1 + edd; e1 = (e1 > 0.f) ? e1 : 0.01f * e1;
            float x0 = __expf(e0), x1 = __expf(e1);
            den += x0 + x1;
            acc = fmaf(x0, z0, fmaf(x1, z1, acc));
        }
        for (; i < end; i += 2) {
            int s = csr_src[i];
            float e = es[s] + edd;
            e = (e > 0.f) ? e : 0.01f * e;
            float x = __expf(e);
            den += x;
            acc = fmaf(x, z[s * HH + j], acc);
        }
        den += __shfl_xor(den, 32);
        acc += __shfl_xor(acc, 32);
        float v = acc / den;
        cval = (v > 0.f) ? v : expm1f(v);
        if (WRITE_C && half == 0)
            cout[(size_t)lt * NLOC * HH + (size_t)d * HH + j] = cval;
    }
    if (POOL) {
        if (half == 0) sred[w][j] = cval;       // -FLT_MAX for invalid waves
        __syncthreads();
        if (threadIdx.x < HH) {
            float m = fmaxf(fmaxf(sred[0][threadIdx.x], sred[1][threadIdx.x]),
                            fmaxf(sred[2][threadIdx.x], sred[3][threadIdx.x]));
            atomicMax(&pooled_u[(size_t)((tbase + lt) * HH + threadIdx.x) * PSTR], fkey(m));
        }
    }
}

// ---------------- GRU over all 24 steps + heads, single block
__global__ void gru_all_kernel(const unsigned int* __restrict__ pooled_u,
                               const float* __restrict__ Wih, const float* __restrict__ Whh,
                               const float* __restrict__ bih, const float* __restrict__ bhh,
                               const float* __restrict__ WI, const float* __restrict__ bI,
                               const float* __restrict__ WR, const float* __restrict__ bR,
                               const float* __restrict__ Ws, const float* __restrict__ bs,
                               const float* __restrict__ cIv, const float* __restrict__ cRv,
                               const float* __restrict__ h0, float* __restrict__ abArr,
                               float* __restrict__ out_newI, float* __restrict__ out_newR,
                               float* __restrict__ h_fin) {
    __shared__ float pooled[HH], hs[HH], gi[96], gh[96], hc[34];
    int tid = threadIdx.x;
    float wih_r[HH], whh_r[HH];
    if (tid < 96) {
        #pragma unroll
        for (int k = 0; k < HH; ++k) {
            wih_r[k] = Wih[tid * HH + k];
            whh_r[k] = Whh[tid * HH + k];
        }
    }
    if (tid < HH) hs[tid] = h0[tid];
    __syncthreads();
    for (int t = 0; t < TT; ++t) {
        if (tid < HH) pooled[tid] = funkey(pooled_u[(size_t)(t * HH + tid) * PSTR]);
        __syncthreads();
        if (tid < 96) {
            float a = bih[tid], g = bhh[tid];
            #pragma unroll
            for (int k = 0; k < HH; ++k) {
                a = fmaf(wih_r[k], pooled[k], a);
                g = fmaf(whh_r[k], hs[k], g);
            }
            gi[tid] = a; gh[tid] = g;
        }
        __syncthreads();
        if (tid < HH) {
            float r  = 1.f / (1.f + expf(-(gi[tid] + gh[tid])));
            float zg = 1.f / (1.f + expf(-(gi[HH + tid] + gh[HH + tid])));
            float nn = tanhf(gi[2 * HH + tid] + r * gh[2 * HH + tid]);
            float hn = (1.f - zg) * nn + zg * hs[tid];
            hs[tid] = hn;
            hc[tid] = hn;
        }
        if (tid == 32) hc[32] = cIv[t];
        if (tid == 33) hc[33] = cRv[t];
        __syncthreads();
        if (tid < PWN) {
            float a = bI[tid];
            #pragma unroll
            for (int k = 0; k < 34; ++k) a = fmaf(WI[tid * 34 + k], hc[k], a);
            out_newI[t * PWN + tid] = a;
        } else if (tid >= 32 && tid < 32 + PWN) {
            int p = tid - 32;
            float a = bR[p];
            #pragma unroll
            for (int k = 0; k < 34; ++k) a = fmaf(WR[p * 34 + k], hc[k], a);
            out_newR[t * PWN + p] = a;
        } else if (tid == 64 || tid == 65) {
            int p = tid - 64;
            float a = bs[p];
            #pragma unroll
            for (int k = 0; k < 34; ++k) a = fmaf(Ws[p * 34 + k], hc[k], a);
            abArr[2 * t + p] = 1.f / (1.f + expf(-a));
        }
        __syncthreads();
    }
    if (tid < HH) h_fin[tid] = hs[tid];
}

// ---------------- SIR rollout for all (n, t)
__global__ void sir_kernel(const float* __restrict__ Nin, const float* __restrict__ Iv,
                           const float* __restrict__ Rv, const float* __restrict__ abArr,
                           float* __restrict__ phyI, float* __restrict__ phyR) {
    int idx = blockIdx.x * blockDim.x + threadIdx.x; // n*TT + t
    if (idx >= NLOC * TT) return;
    int n = idx / TT, t = idx - n * TT;
    float Nv = Nin[n];
    float alpha = abArr[2 * t], beta = abArr[2 * t + 1];
    float lI = Iv[t], lR = Rv[t];
    float* oI = phyI + (size_t)idx * PWN;
    float* oR = phyR + (size_t)idx * PWN;
    #pragma unroll
    for (int p = 0; p < PWN; ++p) {
        float lS = Nv - lI - lR;
        float dI = alpha * lI * (lS / Nv) - beta * lI;
        float dR = beta * lI;
        oI[p] = dI;
        oR[p] = dR;
        lI += dI;
        lR += dR;
    }
}

extern "C" void kernel_launch(void* const* d_in, const int* in_sizes, int n_in,
                              void* d_out, int out_size, void* d_ws, size_t ws_size,
                              hipStream_t stream) {
    const float* dynamic = (const float*)d_in[0];
    const float* cIv = (const float*)d_in[1];
    const float* cRv = (const float*)d_in[2];
    const float* Nin = (const float*)d_in[3];
    const float* Iv  = (const float*)d_in[4];
    const float* Rv  = (const float*)d_in[5];
    const float* h0  = (const float*)d_in[6];
    const float* W1  = (const float*)d_in[7];
    const float* b1  = (const float*)d_in[8];
    const float* aW1 = (const float*)d_in[9];
    const float* ab1 = (const float*)d_in[10];
    const float* W2  = (const float*)d_in[11];
    const float* b2  = (const float*)d_in[12];
    const float* aW2 = (const float*)d_in[13];
    const float* ab2 = (const float*)d_in[14];
    const float* Wih = (const float*)d_in[15];
    const float* Whh = (const float*)d_in[16];
    const float* bih = (const float*)d_in[17];
    const float* bhh = (const float*)d_in[18];
    const float* WI  = (const float*)d_in[19];
    const float* bI  = (const float*)d_in[20];
    const float* WR  = (const float*)d_in[21];
    const float* bR  = (const float*)d_in[22];
    const float* Ws  = (const float*)d_in[23];
    const float* bs  = (const float*)d_in[24];
    const int* esrc  = (const int*)d_in[25];
    const int* edst  = (const int*)d_in[26];
    const int E = in_sizes[25];

    float* out = (float*)d_out;
    float* out_newI = out;                         // (1,24,15)
    float* out_newR = out + TT * PWN;              // (1,24,15)
    float* phyI = out + 2 * TT * PWN;              // (20000,24,15)
    float* phyR = phyI + (size_t)NLOC * TT * PWN;
    float* h_fin = phyR + (size_t)NLOC * TT * PWN; // (1,32)

    // ---------------- workspace layout ----------------
    char* p = (char*)d_ws;
    int* cnt = (int*)p;                 p += (size_t)NLOC * 4;
    int* fill = (int*)p;                p += (size_t)NLOC * 4;
    int* row_ptr = (int*)p;             p += (size_t)(NLOC + 2) * 4;
    int* csr = (int*)p;                 p += (size_t)E * 4;
    unsigned int* pooled_u = (unsigned int*)p; p += (size_t)TT * HH * PSTR * 4;
    float* abArr = (float*)p;           p += (size_t)2 * TT * 4;
    size_t fixed_bytes = (size_t)(p - (char*)d_ws);
    size_t per_t_bytes = (size_t)(2 * NLOC * HH + 2 * NLOC) * 4;
    int B = 1;
    if (ws_size > fixed_bytes + per_t_bytes)
        B = (int)((ws_size - fixed_bytes) / per_t_bytes);
    if (B > TT) B = TT;
    if (B < 1) B = 1;
    float* zb  = (float*)p;             // B * NLOC*HH
    float* cb  = zb + (size_t)B * NLOC * HH;
    float* esb = cb + (size_t)B * NLOC * HH;
    float* edb = esb + (size_t)B * NLOC;

    hipMemsetAsync(cnt, 0, (size_t)2 * NLOC * 4, stream);
    hipMemsetAsync(pooled_u, 0, (size_t)TT * HH * PSTR * 4, stream);

    int egrid = (E + 255) / 256;
    count_kernel<<<egrid, 256, 0, stream>>>(edst, cnt, E);
    scan_kernel<<<1, 1024, 0, stream>>>(cnt, row_ptr, NLOC);
    scatter_kernel<<<egrid, 256, 0, stream>>>(esrc, edst, row_ptr, fill, csr, E);

    const int ngrid = (NLOC + 255) / 256;   // 79
    const int agrid = (NLOC + 3) / 4;       // 5000 (256 threads = 4 waves = 4 dsts)

    for (int tbase = 0; tbase < TT; tbase += B) {
        int Bc = TT - tbase; if (Bc > B) Bc = B;
        dim3 ng(ngrid, Bc), ag(agrid, Bc);
        // layer 1
        node_kernel<INDIM><<<ng, 256, 0, stream>>>(dynamic, (long)TT * INDIM, (long)INDIM, tbase,
                                                   W1, b1, aW1, ab1, zb, esb, edb);
        agg_kernel<true, false><<<ag, 256, 0, stream>>>(row_ptr, csr, zb, esb, edb, cb, pooled_u, tbase);
        // layer 2 (no c materialization; pooled max only)
        node_kernel<HH><<<ng, 256, 0, stream>>>(cb, (long)HH, (long)NLOC * HH, 0,
                                                W2, b2, aW2, ab2, zb, esb, edb);
        agg_kernel<false, true><<<ag, 256, 0, stream>>>(row_ptr, csr, zb, esb, edb, nullptr, pooled_u, tbase);
    }

    gru_all_kernel<<<1, 128, 0, stream>>>(pooled_u, Wih, Whh, bih, bhh,
                                          WI, bI, WR, bR, Ws, bs, cIv, cRv,
                                          h0, abArr, out_newI, out_newR, h_fin);
    sir_kernel<<<(NLOC * TT + 255) / 256, 256, 0, stream>>>(Nin, Iv, Rv, abArr, phyI, phyR);
}

// Round 3
// 1471.910 us; speedup vs baseline: 1.6579x; 1.0410x over previous
//
#include <hip/hip_runtime.h>
#include <math.h>
#include <float.h>

#define NLOC 20000
#define TT   24
#define INDIM 18
#define HH   32
#define PWN  15
#define PSTR 32   // uint stride between pooled keys (128B) to spread atomic lines

__device__ __forceinline__ unsigned int fkey(float f) {
    unsigned int b = __float_as_uint(f);
    return b ^ ((unsigned int)((int)b >> 31) | 0x80000000u);
}
__device__ __forceinline__ float funkey(unsigned int u) {
    return (u & 0x80000000u) ? __uint_as_float(u ^ 0x80000000u) : __uint_as_float(~u);
}

// ---------------- CSR build ----------------
__global__ void count_kernel(const int* __restrict__ dst, int* __restrict__ cnt, int E) {
    int e = blockIdx.x * blockDim.x + threadIdx.x;
    if (e < E) atomicAdd(&cnt[dst[e]], 1);
}

__global__ void scan_kernel(const int* __restrict__ cnt, int* __restrict__ row_ptr, int n) {
    __shared__ int sums[1024];
    const int CH = 20;
    int tid = threadIdx.x;
    int base = tid * CH;
    int local[CH];
    int s = 0;
    #pragma unroll
    for (int i = 0; i < CH; ++i) {
        int idx = base + i;
        int v = (idx < n) ? cnt[idx] : 0;
        local[i] = s;
        s += v;
    }
    sums[tid] = s;
    __syncthreads();
    for (int o = 1; o < 1024; o <<= 1) {
        int v = (tid >= o) ? sums[tid - o] : 0;
        __syncthreads();
        sums[tid] += v;
        __syncthreads();
    }
    int pre = (tid > 0) ? sums[tid - 1] : 0;
    #pragma unroll
    for (int i = 0; i < CH; ++i) {
        int idx = base + i;
        if (idx < n) row_ptr[idx] = pre + local[i];
    }
    if (tid == 1023) row_ptr[n] = sums[1023];
}

__global__ void scatter_kernel(const int* __restrict__ src, const int* __restrict__ dst,
                               const int* __restrict__ row_ptr, int* __restrict__ fill,
                               int* __restrict__ csr_src, int E) {
    int e = blockIdx.x * blockDim.x + threadIdx.x;
    if (e < E) {
        int d = dst[e];
        int pos = row_ptr[d] + atomicAdd(&fill[d], 1);
        csr_src[pos] = src[e];
    }
}

// ---------------- node transform (batched over timesteps via grid.y)
template<int IN>
__global__ void node_kernel(const float* __restrict__ xbase, long nstride, long tstride, int tadd,
                            const float* __restrict__ W, const float* __restrict__ b,
                            const float* __restrict__ aW, const float* __restrict__ ab,
                            float* __restrict__ z, float* __restrict__ es, float* __restrict__ ed) {
    __shared__ float sW[HH * IN];
    __shared__ float sb[HH];
    __shared__ float saW[2 * HH];
    __shared__ float sab;
    int tid = threadIdx.x;
    int lt = blockIdx.y;
    for (int i = tid; i < HH * IN; i += blockDim.x) sW[i] = W[i];
    if (tid < HH) sb[tid] = b[tid];
    if (tid < 2 * HH) saW[tid] = aW[tid];
    if (tid == 0) sab = ab[0];
    __syncthreads();
    int n = blockIdx.x * blockDim.x + tid;
    if (n >= NLOC) return;
    z  += (size_t)lt * NLOC * HH;
    es += (size_t)lt * NLOC;
    ed += (size_t)lt * NLOC;
    float xr[IN];
    const float* xp = xbase + (long)n * nstride + (long)(tadd + lt) * tstride;
    #pragma unroll
    for (int i = 0; i < IN; ++i) xr[i] = xp[i];
    float e_s = 0.f, e_d = sab;
    #pragma unroll
    for (int k = 0; k < HH; ++k) {
        float acc = sb[k];
        #pragma unroll
        for (int i = 0; i < IN; ++i) acc = fmaf(xr[i], sW[k * IN + i], acc);
        z[n * HH + k] = acc;
        e_s = fmaf(saW[k], acc, e_s);
        e_d = fmaf(saW[HH + k], acc, e_d);
    }
    es[n] = e_s;
    ed[n] = e_d;
}

// ---------------- per-dst attention aggregation (+elu), latency-optimized:
// wave-per-dst; all <=64 edge indices preloaded in ONE coalesced load, es gathered
// in ONE instruction, softmax denominator computed by wave-reduction (no loop),
// weighted-z loop uses only shfl broadcasts -> gathers pipeline (no addr dep chain).
template<bool WRITE_C, bool POOL>
__global__ void agg_kernel(const int* __restrict__ row_ptr, const int* __restrict__ csr_src,
                           const float* __restrict__ z, const float* __restrict__ es,
                           const float* __restrict__ ed, float* __restrict__ cout,
                           unsigned int* __restrict__ pooled_u, int tbase) {
    __shared__ float sred[4][HH];
    int lt = blockIdx.y;
    int lane = threadIdx.x & 63;
    int w    = threadIdx.x >> 6;
    int j    = lane & 31;
    int half = lane >> 5;
    int d = blockIdx.x * 4 + w;
    z  += (size_t)lt * NLOC * HH;
    es += (size_t)lt * NLOC;
    ed += (size_t)lt * NLOC;

    float cval = -FLT_MAX;
    if (d < NLOC) {
        int beg = row_ptr[d], end = row_ptr[d + 1];
        int deg = end - beg;
        float edd = ed[d];
        // --- preload phase: one coalesced idx load + one es gather ---
        int il = beg + lane;
        bool valid = (il < end);
        int idx_l = valid ? csr_src[il] : 0;
        float esv = es[idx_l];                    // idx_l==0 for invalid: harmless
        float e_l = esv + edd;
        e_l = (e_l > 0.f) ? e_l : 0.01f * e_l;    // leaky_relu
        float x_l = valid ? __expf(e_l) : 0.f;    // unnormalized softmax weight
        // --- denominator: pure wave reduction ---
        float den = x_l;
        #pragma unroll
        for (int o = 32; o; o >>= 1) den += __shfl_xor(den, o, 64);
        // --- weighted gather loop: 2 edges per instr (halves), 4 pairs unrolled ---
        float acc = 0.f;
        int deg64 = (deg < 64) ? deg : 64;
        int e = half;
        #pragma unroll 4
        for (; e < deg64; e += 2) {
            int   s  = __shfl(idx_l, e, 64);
            float ww = __shfl(x_l,  e, 64);
            acc = fmaf(ww, z[(size_t)s * HH + j], acc);
        }
        // --- tail for deg > 64 (rare): serial per half, also extends denominator ---
        float dent = 0.f;
        for (int i = beg + 64 + half; i < end; i += 2) {
            int s = csr_src[i];
            float ee = es[s] + edd;
            ee = (ee > 0.f) ? ee : 0.01f * ee;
            float xx = __expf(ee);
            dent += xx;
            acc = fmaf(xx, z[(size_t)s * HH + j], acc);
        }
        acc  += __shfl_xor(acc, 32, 64);
        dent += __shfl_xor(dent, 32, 64);
        den  += dent;
        float v = acc / den;
        cval = (v > 0.f) ? v : expm1f(v);          // elu
        if (WRITE_C && half == 0)
            cout[(size_t)lt * NLOC * HH + (size_t)d * HH + j] = cval;
    }
    if (POOL) {
        if (half == 0) sred[w][j] = cval;
        __syncthreads();
        if (threadIdx.x < HH) {
            float m = fmaxf(fmaxf(sred[0][threadIdx.x], sred[1][threadIdx.x]),
                            fmaxf(sred[2][threadIdx.x], sred[3][threadIdx.x]));
            atomicMax(&pooled_u[(size_t)((tbase + lt) * HH + threadIdx.x) * PSTR], fkey(m));
        }
    }
}

// ---------------- GRU over all 24 steps + heads, single block
__global__ void gru_all_kernel(const unsigned int* __restrict__ pooled_u,
                               const float* __restrict__ Wih, const float* __restrict__ Whh,
                               const float* __restrict__ bih, const float* __restrict__ bhh,
                               const float* __restrict__ WI, const float* __restrict__ bI,
                               const float* __restrict__ WR, const float* __restrict__ bR,
                               const float* __restrict__ Ws, const float* __restrict__ bs,
                               const float* __restrict__ cIv, const float* __restrict__ cRv,
                               const float* __restrict__ h0, float* __restrict__ abArr,
                               float* __restrict__ out_newI, float* __restrict__ out_newR,
                               float* __restrict__ h_fin) {
    __shared__ float pooled[HH], hs[HH], gi[96], gh[96], hc[34];
    int tid = threadIdx.x;
    float wih_r[HH], whh_r[HH];
    if (tid < 96) {
        #pragma unroll
        for (int k = 0; k < HH; ++k) {
            wih_r[k] = Wih[tid * HH + k];
            whh_r[k] = Whh[tid * HH + k];
        }
    }
    if (tid < HH) hs[tid] = h0[tid];
    __syncthreads();
    for (int t = 0; t < TT; ++t) {
        if (tid < HH) pooled[tid] = funkey(pooled_u[(size_t)(t * HH + tid) * PSTR]);
        __syncthreads();
        if (tid < 96) {
            float a = bih[tid], g = bhh[tid];
            #pragma unroll
            for (int k = 0; k < HH; ++k) {
                a = fmaf(wih_r[k], pooled[k], a);
                g = fmaf(whh_r[k], hs[k], g);
            }
            gi[tid] = a; gh[tid] = g;
        }
        __syncthreads();
        if (tid < HH) {
            float r  = 1.f / (1.f + expf(-(gi[tid] + gh[tid])));
            float zg = 1.f / (1.f + expf(-(gi[HH + tid] + gh[HH + tid])));
            float nn = tanhf(gi[2 * HH + tid] + r * gh[2 * HH + tid]);
            float hn = (1.f - zg) * nn + zg * hs[tid];
            hs[tid] = hn;
            hc[tid] = hn;
        }
        if (tid == 32) hc[32] = cIv[t];
        if (tid == 33) hc[33] = cRv[t];
        __syncthreads();
        if (tid < PWN) {
            float a = bI[tid];
            #pragma unroll
            for (int k = 0; k < 34; ++k) a = fmaf(WI[tid * 34 + k], hc[k], a);
            out_newI[t * PWN + tid] = a;
        } else if (tid >= 32 && tid < 32 + PWN) {
            int p = tid - 32;
            float a = bR[p];
            #pragma unroll
            for (int k = 0; k < 34; ++k) a = fmaf(WR[p * 34 + k], hc[k], a);
            out_newR[t * PWN + p] = a;
        } else if (tid == 64 || tid == 65) {
            int p = tid - 64;
            float a = bs[p];
            #pragma unroll
            for (int k = 0; k < 34; ++k) a = fmaf(Ws[p * 34 + k], hc[k], a);
            abArr[2 * t + p] = 1.f / (1.f + expf(-a));
        }
        __syncthreads();
    }
    if (tid < HH) h_fin[tid] = hs[tid];
}

// ---------------- SIR rollout for all (n, t)
__global__ void sir_kernel(const float* __restrict__ Nin, const float* __restrict__ Iv,
                           const float* __restrict__ Rv, const float* __restrict__ abArr,
                           float* __restrict__ phyI, float* __restrict__ phyR) {
    int idx = blockIdx.x * blockDim.x + threadIdx.x; // n*TT + t
    if (idx >= NLOC * TT) return;
    int n = idx / TT, t = idx - n * TT;
    float Nv = Nin[n];
    float alpha = abArr[2 * t], beta = abArr[2 * t + 1];
    float lI = Iv[t], lR = Rv[t];
    float* oI = phyI + (size_t)idx * PWN;
    float* oR = phyR + (size_t)idx * PWN;
    #pragma unroll
    for (int p = 0; p < PWN; ++p) {
        float lS = Nv - lI - lR;
        float dI = alpha * lI * (lS / Nv) - beta * lI;
        float dR = beta * lI;
        oI[p] = dI;
        oR[p] = dR;
        lI += dI;
        lR += dR;
    }
}

extern "C" void kernel_launch(void* const* d_in, const int* in_sizes, int n_in,
                              void* d_out, int out_size, void* d_ws, size_t ws_size,
                              hipStream_t stream) {
    const float* dynamic = (const float*)d_in[0];
    const float* cIv = (const float*)d_in[1];
    const float* cRv = (const float*)d_in[2];
    const float* Nin = (const float*)d_in[3];
    const float* Iv  = (const float*)d_in[4];
    const float* Rv  = (const float*)d_in[5];
    const float* h0  = (const float*)d_in[6];
    const float* W1  = (const float*)d_in[7];
    const float* b1  = (const float*)d_in[8];
    const float* aW1 = (const float*)d_in[9];
    const float* ab1 = (const float*)d_in[10];
    const float* W2  = (const float*)d_in[11];
    const float* b2  = (const float*)d_in[12];
    const float* aW2 = (const float*)d_in[13];
    const float* ab2 = (const float*)d_in[14];
    const float* Wih = (const float*)d_in[15];
    const float* Whh = (const float*)d_in[16];
    const float* bih = (const float*)d_in[17];
    const float* bhh = (const float*)d_in[18];
    const float* WI  = (const float*)d_in[19];
    const float* bI  = (const float*)d_in[20];
    const float* WR  = (const float*)d_in[21];
    const float* bR  = (const float*)d_in[22];
    const float* Ws  = (const float*)d_in[23];
    const float* bs  = (const float*)d_in[24];
    const int* esrc  = (const int*)d_in[25];
    const int* edst  = (const int*)d_in[26];
    const int E = in_sizes[25];

    float* out = (float*)d_out;
    float* out_newI = out;                         // (1,24,15)
    float* out_newR = out + TT * PWN;              // (1,24,15)
    float* phyI = out + 2 * TT * PWN;              // (20000,24,15)
    float* phyR = phyI + (size_t)NLOC * TT * PWN;
    float* h_fin = phyR + (size_t)NLOC * TT * PWN; // (1,32)

    // ---------------- workspace layout ----------------
    char* p = (char*)d_ws;
    int* cnt = (int*)p;                 p += (size_t)NLOC * 4;
    int* fill = (int*)p;                p += (size_t)NLOC * 4;
    int* row_ptr = (int*)p;             p += (size_t)(NLOC + 2) * 4;
    int* csr = (int*)p;                 p += (size_t)E * 4;
    unsigned int* pooled_u = (unsigned int*)p; p += (size_t)TT * HH * PSTR * 4;
    float* abArr = (float*)p;           p += (size_t)2 * TT * 4;
    size_t fixed_bytes = (size_t)(p - (char*)d_ws);
    size_t per_t_bytes = (size_t)(2 * NLOC * HH + 2 * NLOC) * 4;
    int B = 1;
    if (ws_size > fixed_bytes + per_t_bytes)
        B = (int)((ws_size - fixed_bytes) / per_t_bytes);
    if (B > TT) B = TT;
    if (B < 1) B = 1;
    float* zb  = (float*)p;             // B * NLOC*HH
    float* cb  = zb + (size_t)B * NLOC * HH;
    float* esb = cb + (size_t)B * NLOC * HH;
    float* edb = esb + (size_t)B * NLOC;

    hipMemsetAsync(cnt, 0, (size_t)2 * NLOC * 4, stream);
    hipMemsetAsync(pooled_u, 0, (size_t)TT * HH * PSTR * 4, stream);

    int egrid = (E + 255) / 256;
    count_kernel<<<egrid, 256, 0, stream>>>(edst, cnt, E);
    scan_kernel<<<1, 1024, 0, stream>>>(cnt, row_ptr, NLOC);
    scatter_kernel<<<egrid, 256, 0, stream>>>(esrc, edst, row_ptr, fill, csr, E);

    const int ngrid = (NLOC + 255) / 256;   // 79
    const int agrid = (NLOC + 3) / 4;       // 5000 (256 threads = 4 waves = 4 dsts)

    for (int tbase = 0; tbase < TT; tbase += B) {
        int Bc = TT - tbase; if (Bc > B) Bc = B;
        dim3 ng(ngrid, Bc), ag(agrid, Bc);
        // layer 1
        node_kernel<INDIM><<<ng, 256, 0, stream>>>(dynamic, (long)TT * INDIM, (long)INDIM, tbase,
                                                   W1, b1, aW1, ab1, zb, esb, edb);
        agg_kernel<true, false><<<ag, 256, 0, stream>>>(row_ptr, csr, zb, esb, edb, cb, pooled_u, tbase);
        // layer 2 (no c materialization; pooled max only)
        node_kernel<HH><<<ng, 256, 0, stream>>>(cb, (long)HH, (long)NLOC * HH, 0,
                                                W2, b2, aW2, ab2, zb, esb, edb);
        agg_kernel<false, true><<<ag, 256, 0, stream>>>(row_ptr, csr, zb, esb, edb, nullptr, pooled_u, tbase);
    }

    gru_all_kernel<<<1, 128, 0, stream>>>(pooled_u, Wih, Whh, bih, bhh,
                                          WI, bI, WR, bR, Ws, bs, cIv, cRv,
                                          h0, abArr, out_newI, out_newR, h_fin);
    sir_kernel<<<(NLOC * TT + 255) / 256, 256, 0, stream>>>(Nin, Iv, Rv, abArr, phyI, phyR);
}

// Round 4
// 1081.986 us; speedup vs baseline: 2.2553x; 1.3604x over previous
//
#include <hip/hip_runtime.h>
#include <math.h>
#include <float.h>

#define NLOC 20000
#define TT   24
#define INDIM 18
#define HH   32
#define PWN  15
#define PSTR 32   // uint stride between pooled keys (128B) to spread atomic lines

__device__ __forceinline__ unsigned int fkey(float f) {
    unsigned int b = __float_as_uint(f);
    return b ^ ((unsigned int)((int)b >> 31) | 0x80000000u);
}
__device__ __forceinline__ float funkey(unsigned int u) {
    return (u & 0x80000000u) ? __uint_as_float(u ^ 0x80000000u) : __uint_as_float(~u);
}

// ---------------- CSR build ----------------
__global__ void count_kernel(const int* __restrict__ dst, int* __restrict__ cnt, int E) {
    int e = blockIdx.x * blockDim.x + threadIdx.x;
    if (e < E) atomicAdd(&cnt[dst[e]], 1);
}

__global__ void scan_kernel(const int* __restrict__ cnt, int* __restrict__ row_ptr, int n) {
    __shared__ int sums[1024];
    const int CH = 20;
    int tid = threadIdx.x;
    int base = tid * CH;
    int local[CH];
    int s = 0;
    #pragma unroll
    for (int i = 0; i < CH; ++i) {
        int idx = base + i;
        int v = (idx < n) ? cnt[idx] : 0;
        local[i] = s;
        s += v;
    }
    sums[tid] = s;
    __syncthreads();
    for (int o = 1; o < 1024; o <<= 1) {
        int v = (tid >= o) ? sums[tid - o] : 0;
        __syncthreads();
        sums[tid] += v;
        __syncthreads();
    }
    int pre = (tid > 0) ? sums[tid - 1] : 0;
    #pragma unroll
    for (int i = 0; i < CH; ++i) {
        int idx = base + i;
        if (idx < n) row_ptr[idx] = pre + local[i];
    }
    if (tid == 1023) row_ptr[n] = sums[1023];
}

__global__ void scatter_kernel(const int* __restrict__ src, const int* __restrict__ dst,
                               const int* __restrict__ row_ptr, int* __restrict__ fill,
                               int* __restrict__ csr_src, int E) {
    int e = blockIdx.x * blockDim.x + threadIdx.x;
    if (e < E) {
        int d = dst[e];
        int pos = row_ptr[d] + atomicAdd(&fill[d], 1);
        csr_src[pos] = src[e];
    }
}

// ---------------- node transform (batched over timesteps via grid.y)
template<int IN>
__global__ void node_kernel(const float* __restrict__ xbase, long nstride, long tstride, int tadd,
                            const float* __restrict__ W, const float* __restrict__ b,
                            const float* __restrict__ aW, const float* __restrict__ ab,
                            float* __restrict__ z, float* __restrict__ es, float* __restrict__ ed) {
    __shared__ float sW[HH * IN];
    __shared__ float sb[HH];
    __shared__ float saW[2 * HH];
    __shared__ float sab;
    int tid = threadIdx.x;
    int lt = blockIdx.y;
    for (int i = tid; i < HH * IN; i += blockDim.x) sW[i] = W[i];
    if (tid < HH) sb[tid] = b[tid];
    if (tid < 2 * HH) saW[tid] = aW[tid];
    if (tid == 0) sab = ab[0];
    __syncthreads();
    int n = blockIdx.x * blockDim.x + tid;
    if (n >= NLOC) return;
    z  += (size_t)lt * NLOC * HH;
    es += (size_t)lt * NLOC;
    ed += (size_t)lt * NLOC;
    float xr[IN];
    const float* xp = xbase + (long)n * nstride + (long)(tadd + lt) * tstride;
    #pragma unroll
    for (int i = 0; i < IN; ++i) xr[i] = xp[i];
    float e_s = 0.f, e_d = sab;
    #pragma unroll
    for (int k = 0; k < HH; ++k) {
        float acc = sb[k];
        #pragma unroll
        for (int i = 0; i < IN; ++i) acc = fmaf(xr[i], sW[k * IN + i], acc);
        z[n * HH + k] = acc;
        e_s = fmaf(saW[k], acc, e_s);
        e_d = fmaf(saW[HH + k], acc, e_d);
    }
    es[n] = e_s;
    ed[n] = e_d;
}

// ---------------- per-dst attention aggregation (+elu):
// wave-per-dst; 64 (src,w) pairs computed from ONE coalesced csr load + es gather,
// denominator by wave shfl-reduce, pairs staged to LDS, then a FIXED fully-unrolled
// 32-pair-per-half loop with uniform ds_read_b64 -> all z-gathers issue together
// (no addr dependence between gathers). Pad slots are (0,0): L1-hit, w=0.
template<bool WRITE_C, bool POOL>
__global__ void agg_kernel(const int* __restrict__ row_ptr, const int* __restrict__ csr_src,
                           const float* __restrict__ z, const float* __restrict__ es,
                           const float* __restrict__ ed, float* __restrict__ cout,
                           unsigned int* __restrict__ pooled_u, int tbase) {
    __shared__ int2  shp[4][64];
    __shared__ float sred[4][HH];
    int lt = blockIdx.y;
    int lane = threadIdx.x & 63;
    int w    = threadIdx.x >> 6;
    int j    = lane & 31;
    int half = lane >> 5;
    int d = blockIdx.x * 4 + w;
    z  += (size_t)lt * NLOC * HH;
    es += (size_t)lt * NLOC;
    ed += (size_t)lt * NLOC;

    int beg = 0, end = 0;
    float edd = 0.f;
    if (d < NLOC) {
        beg = row_ptr[d];
        end = row_ptr[d + 1];
        edd = ed[d];
    }
    // --- preload: one coalesced idx load + one es gather, compute weight ---
    int il = beg + lane;
    bool valid = (il < end);
    int idx_l = valid ? csr_src[il] : 0;
    float ev = es[idx_l] + edd;
    ev = (ev > 0.f) ? ev : 0.01f * ev;             // leaky_relu
    float w_l = valid ? __expf(ev) : 0.f;          // unnormalized softmax weight
    // --- denominator: wave reduction (logits O(1): no max-shift needed) ---
    float den = w_l;
    #pragma unroll
    for (int o = 32; o; o >>= 1) den += __shfl_xor(den, o, 64);
    // --- stage pairs to LDS ---
    shp[w][lane] = make_int2(idx_l, __float_as_int(w_l));
    __syncthreads();
    // --- fixed 32-pair loop per half: uniform LDS reads, batched gathers ---
    float acc0 = 0.f, acc1 = 0.f;
    #pragma unroll
    for (int e = 0; e < 64; e += 4) {
        int2 pa = shp[w][e + half];
        int2 pb = shp[w][e + 2 + half];
        acc0 = fmaf(__int_as_float(pa.y), z[(size_t)pa.x * HH + j], acc0);
        acc1 = fmaf(__int_as_float(pb.y), z[(size_t)pb.x * HH + j], acc1);
    }
    float acc = acc0 + acc1;
    // --- tail for deg > 64 (never taken on this graph; correctness only) ---
    float dent = 0.f;
    for (int i = beg + 64 + half; i < end; i += 2) {
        int s2 = csr_src[i];
        float ee = es[s2] + edd;
        ee = (ee > 0.f) ? ee : 0.01f * ee;
        float xx = __expf(ee);
        dent += xx;
        acc = fmaf(xx, z[(size_t)s2 * HH + j], acc);
    }
    acc  += __shfl_xor(acc, 32, 64);
    dent += __shfl_xor(dent, 32, 64);
    den  += dent;

    float cval = -FLT_MAX;
    if (d < NLOC) {
        float v = acc / den;
        cval = (v > 0.f) ? v : expm1f(v);          // elu
        if (WRITE_C && half == 0)
            cout[(size_t)lt * NLOC * HH + (size_t)d * HH + j] = cval;
    }
    if (POOL) {
        if (half == 0) sred[w][j] = cval;
        __syncthreads();
        if (threadIdx.x < HH) {
            float m = fmaxf(fmaxf(sred[0][threadIdx.x], sred[1][threadIdx.x]),
                            fmaxf(sred[2][threadIdx.x], sred[3][threadIdx.x]));
            atomicMax(&pooled_u[(size_t)((tbase + lt) * HH + threadIdx.x) * PSTR], fkey(m));
        }
    }
}

// ---------------- GRU over all 24 steps + heads, single block
__global__ void gru_all_kernel(const unsigned int* __restrict__ pooled_u,
                               const float* __restrict__ Wih, const float* __restrict__ Whh,
                               const float* __restrict__ bih, const float* __restrict__ bhh,
                               const float* __restrict__ WI, const float* __restrict__ bI,
                               const float* __restrict__ WR, const float* __restrict__ bR,
                               const float* __restrict__ Ws, const float* __restrict__ bs,
                               const float* __restrict__ cIv, const float* __restrict__ cRv,
                               const float* __restrict__ h0, float* __restrict__ abArr,
                               float* __restrict__ out_newI, float* __restrict__ out_newR,
                               float* __restrict__ h_fin) {
    __shared__ float pooled[HH], hs[HH], gi[96], gh[96], hc[34];
    int tid = threadIdx.x;
    float wih_r[HH], whh_r[HH];
    if (tid < 96) {
        #pragma unroll
        for (int k = 0; k < HH; ++k) {
            wih_r[k] = Wih[tid * HH + k];
            whh_r[k] = Whh[tid * HH + k];
        }
    }
    if (tid < HH) hs[tid] = h0[tid];
    __syncthreads();
    for (int t = 0; t < TT; ++t) {
        if (tid < HH) pooled[tid] = funkey(pooled_u[(size_t)(t * HH + tid) * PSTR]);
        __syncthreads();
        if (tid < 96) {
            float a = bih[tid], g = bhh[tid];
            #pragma unroll
            for (int k = 0; k < HH; ++k) {
                a = fmaf(wih_r[k], pooled[k], a);
                g = fmaf(whh_r[k], hs[k], g);
            }
            gi[tid] = a; gh[tid] = g;
        }
        __syncthreads();
        if (tid < HH) {
            float r  = 1.f / (1.f + expf(-(gi[tid] + gh[tid])));
            float zg = 1.f / (1.f + expf(-(gi[HH + tid] + gh[HH + tid])));
            float nn = tanhf(gi[2 * HH + tid] + r * gh[2 * HH + tid]);
            float hn = (1.f - zg) * nn + zg * hs[tid];
            hs[tid] = hn;
            hc[tid] = hn;
        }
        if (tid == 32) hc[32] = cIv[t];
        if (tid == 33) hc[33] = cRv[t];
        __syncthreads();
        if (tid < PWN) {
            float a = bI[tid];
            #pragma unroll
            for (int k = 0; k < 34; ++k) a = fmaf(WI[tid * 34 + k], hc[k], a);
            out_newI[t * PWN + tid] = a;
        } else if (tid >= 32 && tid < 32 + PWN) {
            int p = tid - 32;
            float a = bR[p];
            #pragma unroll
            for (int k = 0; k < 34; ++k) a = fmaf(WR[p * 34 + k], hc[k], a);
            out_newR[t * PWN + p] = a;
        } else if (tid == 64 || tid == 65) {
            int p = tid - 64;
            float a = bs[p];
            #pragma unroll
            for (int k = 0; k < 34; ++k) a = fmaf(Ws[p * 34 + k], hc[k], a);
            abArr[2 * t + p] = 1.f / (1.f + expf(-a));
        }
        __syncthreads();
    }
    if (tid < HH) h_fin[tid] = hs[tid];
}

// ---------------- SIR rollout for all (n, t)
__global__ void sir_kernel(const float* __restrict__ Nin, const float* __restrict__ Iv,
                           const float* __restrict__ Rv, const float* __restrict__ abArr,
                           float* __restrict__ phyI, float* __restrict__ phyR) {
    int idx = blockIdx.x * blockDim.x + threadIdx.x; // n*TT + t
    if (idx >= NLOC * TT) return;
    int n = idx / TT, t = idx - n * TT;
    float Nv = Nin[n];
    float alpha = abArr[2 * t], beta = abArr[2 * t + 1];
    float lI = Iv[t], lR = Rv[t];
    float* oI = phyI + (size_t)idx * PWN;
    float* oR = phyR + (size_t)idx * PWN;
    #pragma unroll
    for (int p = 0; p < PWN; ++p) {
        float lS = Nv - lI - lR;
        float dI = alpha * lI * (lS / Nv) - beta * lI;
        float dR = beta * lI;
        oI[p] = dI;
        oR[p] = dR;
        lI += dI;
        lR += dR;
    }
}

extern "C" void kernel_launch(void* const* d_in, const int* in_sizes, int n_in,
                              void* d_out, int out_size, void* d_ws, size_t ws_size,
                              hipStream_t stream) {
    const float* dynamic = (const float*)d_in[0];
    const float* cIv = (const float*)d_in[1];
    const float* cRv = (const float*)d_in[2];
    const float* Nin = (const float*)d_in[3];
    const float* Iv  = (const float*)d_in[4];
    const float* Rv  = (const float*)d_in[5];
    const float* h0  = (const float*)d_in[6];
    const float* W1  = (const float*)d_in[7];
    const float* b1  = (const float*)d_in[8];
    const float* aW1 = (const float*)d_in[9];
    const float* ab1 = (const float*)d_in[10];
    const float* W2  = (const float*)d_in[11];
    const float* b2  = (const float*)d_in[12];
    const float* aW2 = (const float*)d_in[13];
    const float* ab2 = (const float*)d_in[14];
    const float* Wih = (const float*)d_in[15];
    const float* Whh = (const float*)d_in[16];
    const float* bih = (const float*)d_in[17];
    const float* bhh = (const float*)d_in[18];
    const float* WI  = (const float*)d_in[19];
    const float* bI  = (const float*)d_in[20];
    const float* WR  = (const float*)d_in[21];
    const float* bR  = (const float*)d_in[22];
    const float* Ws  = (const float*)d_in[23];
    const float* bs  = (const float*)d_in[24];
    const int* esrc  = (const int*)d_in[25];
    const int* edst  = (const int*)d_in[26];
    const int E = in_sizes[25];

    float* out = (float*)d_out;
    float* out_newI = out;                         // (1,24,15)
    float* out_newR = out + TT * PWN;              // (1,24,15)
    float* phyI = out + 2 * TT * PWN;              // (20000,24,15)
    float* phyR = phyI + (size_t)NLOC * TT * PWN;
    float* h_fin = phyR + (size_t)NLOC * TT * PWN; // (1,32)

    // ---------------- workspace layout ----------------
    char* p = (char*)d_ws;
    int* cnt = (int*)p;                 p += (size_t)NLOC * 4;
    int* fill = (int*)p;                p += (size_t)NLOC * 4;
    int* row_ptr = (int*)p;             p += (size_t)(NLOC + 2) * 4;
    int* csr = (int*)p;                 p += (size_t)E * 4;
    unsigned int* pooled_u = (unsigned int*)p; p += (size_t)TT * HH * PSTR * 4;
    float* abArr = (float*)p;           p += (size_t)2 * TT * 4;
    size_t fixed_bytes = (size_t)(p - (char*)d_ws);
    size_t per_t_bytes = (size_t)(2 * NLOC * HH + 2 * NLOC) * 4;
    int B = 1;
    if (ws_size > fixed_bytes + per_t_bytes)
        B = (int)((ws_size - fixed_bytes) / per_t_bytes);
    if (B > TT) B = TT;
    if (B < 1) B = 1;
    float* zb  = (float*)p;             // B * NLOC*HH
    float* cb  = zb + (size_t)B * NLOC * HH;
    float* esb = cb + (size_t)B * NLOC * HH;
    float* edb = esb + (size_t)B * NLOC;

    hipMemsetAsync(cnt, 0, (size_t)2 * NLOC * 4, stream);
    hipMemsetAsync(pooled_u, 0, (size_t)TT * HH * PSTR * 4, stream);

    int egrid = (E + 255) / 256;
    count_kernel<<<egrid, 256, 0, stream>>>(edst, cnt, E);
    scan_kernel<<<1, 1024, 0, stream>>>(cnt, row_ptr, NLOC);
    scatter_kernel<<<egrid, 256, 0, stream>>>(esrc, edst, row_ptr, fill, csr, E);

    const int ngrid = (NLOC + 255) / 256;   // 79
    const int agrid = (NLOC + 3) / 4;       // 5000 (256 threads = 4 waves = 4 dsts)

    for (int tbase = 0; tbase < TT; tbase += B) {
        int Bc = TT - tbase; if (Bc > B) Bc = B;
        dim3 ng(ngrid, Bc), ag(agrid, Bc);
        // layer 1
        node_kernel<INDIM><<<ng, 256, 0, stream>>>(dynamic, (long)TT * INDIM, (long)INDIM, tbase,
                                                   W1, b1, aW1, ab1, zb, esb, edb);
        agg_kernel<true, false><<<ag, 256, 0, stream>>>(row_ptr, csr, zb, esb, edb, cb, pooled_u, tbase);
        // layer 2 (no c materialization; pooled max only)
        node_kernel<HH><<<ng, 256, 0, stream>>>(cb, (long)HH, (long)NLOC * HH, 0,
                                                W2, b2, aW2, ab2, zb, esb, edb);
        agg_kernel<false, true><<<ag, 256, 0, stream>>>(row_ptr, csr, zb, esb, edb, nullptr, pooled_u, tbase);
    }

    gru_all_kernel<<<1, 128, 0, stream>>>(pooled_u, Wih, Whh, bih, bhh,
                                          WI, bI, WR, bR, Ws, bs, cIv, cRv,
                                          h0, abArr, out_newI, out_newR, h_fin);
    sir_kernel<<<(NLOC * TT + 255) / 256, 256, 0, stream>>>(Nin, Iv, Rv, abArr, phyI, phyR);
}